// Round 2
// baseline (223.615 us; speedup 1.0000x reference)
//
#include <hip/hip_runtime.h>

#define H_ 256
#define P_ 16
#define KOCC 8
#define KSUBJ 16
#define O_ 128
#define CAPMAX 2048
#define RMASK 0xFFFFF  // row ids < 2^20 (N=131072 = 2^17); subj in bits 20..23

typedef __attribute__((ext_vector_type(8))) __bf16 bf16x8;
typedef __attribute__((ext_vector_type(4))) float f32x4;

__device__ __forceinline__ bf16x8 load_bf8(const float* p) {
  float4 a = *(const float4*)p;
  float4 b = *(const float4*)(p + 4);
  bf16x8 r;
  r[0] = (__bf16)a.x; r[1] = (__bf16)a.y; r[2] = (__bf16)a.z; r[3] = (__bf16)a.w;
  r[4] = (__bf16)b.x; r[5] = (__bf16)b.y; r[6] = (__bf16)b.z; r[7] = (__bf16)b.w;
  return r;
}

__device__ __forceinline__ bf16x8 cvt_bf8(float4 a, float4 b) {
  bf16x8 r;
  r[0] = (__bf16)a.x; r[1] = (__bf16)a.y; r[2] = (__bf16)a.z; r[3] = (__bf16)a.w;
  r[4] = (__bf16)b.x; r[5] = (__bf16)b.y; r[6] = (__bf16)b.z; r[7] = (__bf16)b.w;
  return r;
}

__device__ __forceinline__ float rsum16(float v) {
  v += __shfl_xor(v, 1);
  v += __shfl_xor(v, 2);
  v += __shfl_xor(v, 4);
  v += __shfl_xor(v, 8);
  return v;
}

// Pass 1: bucket rows by global occurrence id, packing row | (subj<<20) so the
// main kernel needs a single gather level. 128 blocks x 1024 thr x 1 elem:
// full-GPU-width reads; 128-deep global atomics per counter (fine).
__global__ __launch_bounds__(1024) void scatter_kernel(
    const int* __restrict__ xp, const int* __restrict__ xo,
    const int* __restrict__ xs,
    int* counts, int* brows, int n, int cap) {
  __shared__ int hist[O_];
  __shared__ int basev[O_];
  int tid = threadIdx.x;
  if (tid < O_) hist[tid] = 0;
  __syncthreads();
  int i = blockIdx.x * 1024 + tid;
  int be = 0, pos = -1, pack = 0;
  if (i < n) {
    be = xp[i] * KOCC + xo[i];
    pack = i | (xs[i] << 20);
    pos = atomicAdd(&hist[be], 1);
  }
  __syncthreads();
  if (tid < O_) basev[tid] = atomicAdd(&counts[tid], hist[tid]);
  __syncthreads();
  if (pos >= 0) {
    int idx = basev[be] + pos;
    if (idx < cap) brows[be * cap + idx] = pack;
  }
}

// Issue the 16 batched X loads for one 16-row group (row ids prefetched).
__device__ __forceinline__ void issue_x(
    const float* __restrict__ X, int rida, int quad, float4* ta, float4* tb) {
  const float* xr = X + (size_t)rida * H_ + quad * 8;
#pragma unroll
  for (int kk = 0; kk < 8; ++kk) {
    const float4* s = (const float4*)(xr + kk * 32);
    ta[kk] = s[0];
    tb[kk] = s[1];
  }
}

// Consume one group: cvt -> 24 MFMA -> 3 softmaxes per row -> scatter store.
__device__ __forceinline__ void process_group(
    const bf16x8* __restrict__ Bfrag, int lane, int col, int quad,
    int p, int occl, bool v1, float bias0, float bias1, float bias2,
    int pkv, int rem, const float4* ta, const float4* tb,
    float* __restrict__ out, int n) {
  f32x4 acc0 = {0.f, 0.f, 0.f, 0.f};
  f32x4 acc1 = {0.f, 0.f, 0.f, 0.f};
  f32x4 acc2 = {0.f, 0.f, 0.f, 0.f};
#pragma unroll
  for (int kk = 0; kk < 8; ++kk) {
    bf16x8 a = cvt_bf8(ta[kk], tb[kk]);
    acc0 = __builtin_amdgcn_mfma_f32_16x16x32_bf16(a, Bfrag[kk * 64 + lane], acc0, 0, 0, 0);
    acc1 = __builtin_amdgcn_mfma_f32_16x16x32_bf16(a, Bfrag[(8 + kk) * 64 + lane], acc1, 0, 0, 0);
    acc2 = __builtin_amdgcn_mfma_f32_16x16x32_bf16(a, Bfrag[(16 + kk) * 64 + lane], acc2, 0, 0, 0);
  }
#pragma unroll
  for (int r = 0; r < 4; ++r) {
    int rloc = quad * 4 + r;
    bool rv = rloc < rem;
    int pkr = __shfl(pkv, rloc);     // one shuffle gives row id AND subject
    int ridr = pkr & RMASK;
    int tsub = pkr >> 20;
    float e0 = __expf(acc0[r] + bias0);
    float s0 = rsum16(e0);
    float p0 = __shfl(e0, quad * 16 + p) * __builtin_amdgcn_rcpf(s0);
    float e1 = v1 ? __expf(acc1[r] + bias1) : 0.0f;
    float s1 = rsum16(e1);
    float p1 = __shfl(e1, quad * 16 + occl) * __builtin_amdgcn_rcpf(s1);
    float e2 = __expf(acc2[r] + bias2);
    float s2 = rsum16(e2);
    float p2 = __shfl(e2, quad * 16 + tsub) * __builtin_amdgcn_rcpf(s2);
    if (col == 0 && rv) {
      float po = p0 * p1;
      out[ridr] = p0;
      out[n + ridr] = po;
      out[2 * n + ridr] = po * p2;
    }
  }
}

// Pass 2: grid 512 = 128 buckets x 4 chunks, 4 waves/block, 2 blocks/CU.
// Each wave owns ~4 groups (stride 256 rows in the bucket). ALL group packed
// indices are prefetched up-front (independent loads, static unroll — no
// runtime array indexing, rule #20), so the steady-state loop carries only
// the register-double-buffered X loads: issue group j+1, fence, process j.
// launch_bounds(256,2) keeps the 2x64-reg X buffers in registers.
__global__ __launch_bounds__(256, 2) void hsm_main(
    const float* __restrict__ X,
    const float* __restrict__ Wp, const float* __restrict__ bp,
    const float* __restrict__ Wo, const float* __restrict__ bo,
    const float* __restrict__ Ws, const float* __restrict__ bs,
    const int* __restrict__ counts, const int* __restrict__ brows,
    float* __restrict__ out, int n, int cap) {
  int b = blockIdx.x & 127;      // bucket; 4 chunks of a bucket share an XCD
  int chunk = blockIdx.x >> 7;   // 0..3
  int count = counts[b];
  if (count > cap) count = cap;
  int p = b >> 3;
  int occl = b & 7;

  // --- Stage B fragments into LDS: [head][kk][lane] x 8 bf16 (16 B) ---
  __shared__ __bf16 Bf[3 * 8 * 64 * 8];  // 24 KB
  {
    int t = threadIdx.x;
#pragma unroll
    for (int it = 0; it < 6; ++it) {
      int fid = it * 256 + t;          // 0..1535
      int lane_f = fid & 63;
      int hk = fid >> 6;               // 0..23
      int head = hk >> 3, kk = hk & 7;
      int colf = lane_f & 15, quadf = lane_f >> 4;
      const float* src;
      if (head == 0)      src = Wp + colf * H_;
      else if (head == 1) src = Wo + (p * KOCC + (colf & 7)) * H_;
      else                src = Ws + (b * KSUBJ + colf) * H_;
      bf16x8 v = load_bf8(src + kk * 32 + quadf * 8);
      *(bf16x8*)&Bf[(size_t)fid * 8] = v;
    }
  }
  __syncthreads();

  int lane = threadIdx.x & 63;
  int wave = threadIdx.x >> 6;
  int col = lane & 15;
  int quad = lane >> 4;

  bool v1 = col < KOCC;
  float bias0 = bp[col];
  float bias1 = v1 ? bo[p * KOCC + col] : 0.0f;
  float bias2 = bs[b * KSUBJ + col];

  const int* brow_b = brows + b * cap;
  const bf16x8* Bfrag = (const bf16x8*)Bf;

  int base = chunk * 64 + wave * 16;   // row base; groups at base + 256*j
  if (base >= count) return;
  int ng = (count - base + 255) >> 8;  // 1..8 (cap 2048 / stride 256)

  // Prefetch ALL packed group entries (independent gathers, one latency).
  int pk[8];
#pragma unroll
  for (int j = 0; j < 8; ++j) {
    pk[j] = 0;
    if (j < ng) {
      int bj = base + (j << 8);
      int rem = count - bj;
      pk[j] = brow_b[bj + (col < rem ? col : rem - 1)];
    }
  }

  float4 taA[8], tbA[8], taB[8], tbB[8];
  issue_x(X, pk[0] & RMASK, quad, taA, tbA);
#pragma unroll
  for (int j = 0; j < 8; ++j) {
    if (j >= ng) break;
    if (j + 1 < ng)
      issue_x(X, pk[(j + 1) & 7] & RMASK, quad,
              (j & 1) ? taA : taB, (j & 1) ? tbA : tbB);
    __builtin_amdgcn_sched_barrier(0);   // next group's loads stay above consume
    process_group(Bfrag, lane, col, quad, p, occl, v1, bias0, bias1, bias2,
                  pk[j], count - (base + (j << 8)),
                  (j & 1) ? taB : taA, (j & 1) ? tbB : tbA, out, n);
  }
}

extern "C" void kernel_launch(void* const* d_in, const int* in_sizes, int n_in,
                              void* d_out, int out_size, void* d_ws, size_t ws_size,
                              hipStream_t stream) {
  const float* X  = (const float*)d_in[0];
  const float* Wp = (const float*)d_in[1];
  const float* bp = (const float*)d_in[2];
  const float* Wo = (const float*)d_in[3];
  const float* bo = (const float*)d_in[4];
  const float* Ws = (const float*)d_in[5];
  const float* bs = (const float*)d_in[6];
  const int* xp   = (const int*)d_in[7];
  const int* xo   = (const int*)d_in[8];
  const int* xs   = (const int*)d_in[9];
  float* out = (float*)d_out;
  int n = in_sizes[7];

  int* wsI = (int*)d_ws;
  int* counts = wsI;            // 128 ints
  int* brows = wsI + 128;       // 128 * cap ints (packed row|subj<<20)
  long avail = (long)(ws_size / 4) - 128;
  int cap = (int)(avail / O_);
  if (cap > CAPMAX) cap = CAPMAX;
  if (cap < 1) cap = 1;

  hipMemsetAsync(counts, 0, O_ * sizeof(int), stream);
  scatter_kernel<<<dim3((n + 1023) / 1024), dim3(1024), 0, stream>>>(
      xp, xo, xs, counts, brows, n, cap);
  hsm_main<<<dim3(O_ * 4), dim3(256), 0, stream>>>(X, Wp, bp, Wo, bo, Ws, bs,
                                                   counts, brows, out, n, cap);
}